// Round 14
// baseline (4960.149 us; speedup 1.0000x reference)
//
#include <hip/hip_runtime.h>

typedef _Float16 f16;
typedef _Float16 f16x8 __attribute__((ext_vector_type(8)));
typedef float f32x4 __attribute__((ext_vector_type(4)));
typedef unsigned int u32;
typedef u32 u32x4 __attribute__((ext_vector_type(4)));
typedef unsigned long long u64;

#define TT 512
#define BB 512
#define DD 256
#define HH 512

// ws layout (bytes)
#define WPACK_BYTES (32*4*24*64*8*2)          // 3,145,728
#define HBUF_OFF    (WPACK_BYTES)
#define HQ_SLOT     (BB*HH/4)                 // u64s per slot = 65536
#define HBUF_BYTES  (4*BB*HH*2)               // 4 rotating slots = 2 MB

__device__ __forceinline__ float sigf(float v) {
    return __frcp_rn(1.0f + __expf(-v));
}
__device__ __forceinline__ float tanh_fast(float v) {
    float e = __expf(2.0f * fminf(v, 15.0f));
    return 1.0f - 2.0f * __frcp_rn(e + 1.0f);
}

// Pre-pack W = [W_ih | W_hh] (f32) into per-block, per-fragment f16 layout:
// Wp[ji][nt][ks][lane][8]  with gate row g = nt*512 + ji*16 + (lane&15),
// k = ks*32 + (lane>>4)*8 + j  (k<256 -> W_ih, else W_hh).
__global__ void pack_w(const float* __restrict__ W_ih,
                       const float* __restrict__ W_hh,
                       f16* __restrict__ Wp) {
    int tid = blockIdx.x * 256 + threadIdx.x;   // 32*4*24*64 = 196608 total
    if (tid >= 32*4*24*64) return;
    int lane = tid & 63;
    int rest = tid >> 6;
    int ks   = rest % 24;
    int t3   = rest / 24;
    int nt   = t3 & 3;
    int ji   = t3 >> 2;
    int g  = nt*512 + ji*16 + (lane & 15);
    int k0 = ks*32 + ((lane >> 4) & 3)*8;
    const float* src = (k0 < 256) ? (W_ih + (size_t)g*DD + k0)
                                  : (W_hh + (size_t)g*HH + (k0 - 256));
    f16x8 v;
    #pragma unroll
    for (int j = 0; j < 8; ++j) v[j] = (f16)src[j];
    *(f16x8*)(Wp + (size_t)tid*8) = v;
}

// 16 x 16B device-scope (sc1) loads at 64B stride, vmcnt(0) fused (no hoist
// gap). Data arrives WITH the freshness markers — single round trip.
#define LDH16_SC1(A, p) asm volatile(                                  \
    "global_load_dwordx4 %0, %16, off sc1\n\t"                         \
    "global_load_dwordx4 %1, %16, off offset:64 sc1\n\t"               \
    "global_load_dwordx4 %2, %16, off offset:128 sc1\n\t"              \
    "global_load_dwordx4 %3, %16, off offset:192 sc1\n\t"              \
    "global_load_dwordx4 %4, %16, off offset:256 sc1\n\t"              \
    "global_load_dwordx4 %5, %16, off offset:320 sc1\n\t"              \
    "global_load_dwordx4 %6, %16, off offset:384 sc1\n\t"              \
    "global_load_dwordx4 %7, %16, off offset:448 sc1\n\t"              \
    "global_load_dwordx4 %8, %16, off offset:512 sc1\n\t"              \
    "global_load_dwordx4 %9, %16, off offset:576 sc1\n\t"              \
    "global_load_dwordx4 %10, %16, off offset:640 sc1\n\t"             \
    "global_load_dwordx4 %11, %16, off offset:704 sc1\n\t"             \
    "global_load_dwordx4 %12, %16, off offset:768 sc1\n\t"             \
    "global_load_dwordx4 %13, %16, off offset:832 sc1\n\t"             \
    "global_load_dwordx4 %14, %16, off offset:896 sc1\n\t"             \
    "global_load_dwordx4 %15, %16, off offset:960 sc1\n\t"             \
    "s_waitcnt vmcnt(0)"                                               \
    : "=&v"((A)[0]), "=&v"((A)[1]), "=&v"((A)[2]), "=&v"((A)[3]),      \
      "=&v"((A)[4]), "=&v"((A)[5]), "=&v"((A)[6]), "=&v"((A)[7]),      \
      "=&v"((A)[8]), "=&v"((A)[9]), "=&v"((A)[10]), "=&v"((A)[11]),    \
      "=&v"((A)[12]), "=&v"((A)[13]), "=&v"((A)[14]), "=&v"((A)[15])   \
    : "v"(p) : "memory")

// 16 x 16B contiguous (256B), sc1, for the classifier head.
#define LDH256_SC1(A, p) asm volatile(                                 \
    "global_load_dwordx4 %0, %16, off sc1\n\t"                         \
    "global_load_dwordx4 %1, %16, off offset:16 sc1\n\t"               \
    "global_load_dwordx4 %2, %16, off offset:32 sc1\n\t"               \
    "global_load_dwordx4 %3, %16, off offset:48 sc1\n\t"               \
    "global_load_dwordx4 %4, %16, off offset:64 sc1\n\t"               \
    "global_load_dwordx4 %5, %16, off offset:80 sc1\n\t"               \
    "global_load_dwordx4 %6, %16, off offset:96 sc1\n\t"               \
    "global_load_dwordx4 %7, %16, off offset:112 sc1\n\t"              \
    "global_load_dwordx4 %8, %16, off offset:128 sc1\n\t"              \
    "global_load_dwordx4 %9, %16, off offset:144 sc1\n\t"              \
    "global_load_dwordx4 %10, %16, off offset:160 sc1\n\t"             \
    "global_load_dwordx4 %11, %16, off offset:176 sc1\n\t"             \
    "global_load_dwordx4 %12, %16, off offset:192 sc1\n\t"             \
    "global_load_dwordx4 %13, %16, off offset:208 sc1\n\t"             \
    "global_load_dwordx4 %14, %16, off offset:224 sc1\n\t"             \
    "global_load_dwordx4 %15, %16, off offset:240 sc1\n\t"             \
    "s_waitcnt vmcnt(0)"                                               \
    : "=&v"((A)[0]), "=&v"((A)[1]), "=&v"((A)[2]), "=&v"((A)[3]),      \
      "=&v"((A)[4]), "=&v"((A)[5]), "=&v"((A)[6]), "=&v"((A)[7]),      \
      "=&v"((A)[8]), "=&v"((A)[9]), "=&v"((A)[10]), "=&v"((A)[11]),    \
      "=&v"((A)[12]), "=&v"((A)[13]), "=&v"((A)[14]), "=&v"((A)[15])   \
    : "v"(p) : "memory")

// Sentinel: f16 0xFFFF (-NaN). h = og*tanh(c) is always finite -> never NaN.
// Each producer lane's 8B quad store is single-instruction atomic, so a chunk
// whose two quad-markers (f16[3], f16[7]) are non-sentinel is complete.
__device__ __forceinline__ bool chunk_ok(const f16x8& c) {
    u32x4 t = __builtin_bit_cast(u32x4, c);
    return ((t.y >> 16) != 0xFFFFu) && ((t.w >> 16) != 0xFFFFu);
}

// tail / prologue: acc = bias + x(snext)*W_ih, tight raw-load burst
// immediately before use (R12/R13 lesson: do NOT issue x earlier).
__device__ __forceinline__ void x_tail(
    int snext, f32x4 (&acc)[4], const float* __restrict__ xrow,
    const f16x8* __restrict__ Wlds, const float (&bias)[4][4], int lane)
{
    const float* xs = xrow + (size_t)snext * DD;
    float4 na[8], nb[8];
    #pragma unroll
    for (int ks = 0; ks < 8; ++ks) {
        na[ks] = *(const float4*)(xs + ks*32);
        nb[ks] = *(const float4*)(xs + ks*32 + 4);
    }
    #pragma unroll
    for (int nt = 0; nt < 4; ++nt)
        acc[nt] = (f32x4){bias[nt][0], bias[nt][1], bias[nt][2], bias[nt][3]};
    #pragma unroll
    for (int ks = 0; ks < 8; ++ks) {
        f16x8 a;
        a[0]=(f16)na[ks].x; a[1]=(f16)na[ks].y; a[2]=(f16)na[ks].z; a[3]=(f16)na[ks].w;
        a[4]=(f16)nb[ks].x; a[5]=(f16)nb[ks].y; a[6]=(f16)nb[ks].z; a[7]=(f16)nb[ks].w;
        #pragma unroll
        for (int nt = 0; nt < 4; ++nt)
            acc[nt] = __builtin_amdgcn_mfma_f32_16x16x32_f16(
                Wlds[(nt*24 + ks)*64 + lane], a, acc[nt], 0, 0, 0);
    }
}

// One R11-verbatim sentinel pipeline step for one batch group:
// poll-with-data (s>0) + slot clear + rec MFMA, cell, vmcnt(0), h store,
// x tail. All state named locals -> registers.
__device__ __forceinline__ void step_pipe(
    int s, f32x4 (&acc)[4], float (&c)[4],
    const f16x8* __restrict__ Wlds, u64* __restrict__ hq,
    int hrow_q, int hoff_q, const float* __restrict__ xrow,
    const float (&bias)[4][4], int lane)
{
    if (s > 0) {
        const u64* hb = hq + (size_t)(s & 3) * HQ_SLOT + hrow_q;
        f16x8 Ah[16];
        for (;;) {
            LDH16_SC1(Ah, hb);
            bool ok = true;
            #pragma unroll
            for (int ks = 0; ks < 16; ++ks) ok = ok && chunk_ok(Ah[ks]);
            if (__all(ok)) break;
            __builtin_amdgcn_s_sleep(2);
        }
        // clear own region of slot (s+3)%4 for h(s+3): poll success proves the
        // group community (32 blocks sharing p mod 4) finished reading h(s-1).
        if (s + 3 <= TT)
            __hip_atomic_store(hq + (size_t)((s + 3) & 3) * HQ_SLOT + hoff_q,
                               0xFFFFFFFFFFFFFFFFull, __ATOMIC_RELAXED,
                               __HIP_MEMORY_SCOPE_AGENT);
        #pragma unroll
        for (int ks = 0; ks < 16; ++ks)
            #pragma unroll
            for (int nt = 0; nt < 4; ++nt)
                acc[nt] = __builtin_amdgcn_mfma_f32_16x16x32_f16(
                    Wlds[(nt*24 + ks + 8)*64 + lane], Ah[ks], acc[nt], 0, 0, 0);
    } else {
        // s == 0: slot 3 clear for uniformity (memset sentinel; unread).
        __hip_atomic_store(hq + (size_t)3 * HQ_SLOT + hoff_q,
                           0xFFFFFFFFFFFFFFFFull, __ATOMIC_RELAXED,
                           __HIP_MEMORY_SCOPE_AGENT);
    }

    // cell: lane = (batch, 4 consecutive units) for all 4 gates
    union { u64 q; f16 h4[4]; } H;
    #pragma unroll
    for (int r = 0; r < 4; ++r) {
        float ig = sigf(acc[0][r]);
        float fg = sigf(acc[1][r]);
        float gg = tanh_fast(acc[2][r]);
        float og = sigf(acc[3][r]);
        c[r] = fg * c[r] + ig * gg;
        H.h4[r] = (f16)(og * tanh_fast(c[r]));
    }

    // release: drain (old, overlapped) clear, store h, done — no flags
    asm volatile("s_waitcnt vmcnt(0)" ::: "memory");
    __hip_atomic_store(hq + (size_t)((s + 1) & 3) * HQ_SLOT + hoff_q, H.q,
                       __ATOMIC_RELAXED, __HIP_MEMORY_SCOPE_AGENT);

    // tail: x(s+1), tight burst, off the peer-critical path
    if (s + 1 < TT) x_tail(s + 1, acc, xrow, Wlds, bias, lane);
}

// Persistent LSTM: 128 blocks x 256 threads, block = (ji = blk&31, p = blk>>5).
// Each wave runs TWO independent R11-sentinel pipelines: A = batch group p,
// B = group p+4, same ji (shared 96KB W slice in LDS). Alternating A/B steps
// phase-offsets each group's producers ~half a period ahead of its consumers:
// the store->L3->poll chain wait overlaps the other pipeline's compute.
__launch_bounds__(256, 1)
__global__ void lstm_fused(const float* __restrict__ x,
                           const float* __restrict__ b_ih,
                           const float* __restrict__ b_hh,
                           const float* __restrict__ W_fc,
                           const float* __restrict__ b_fc,
                           const f16* __restrict__ Wp,
                           f16* __restrict__ hbuf,
                           float* __restrict__ out) {
    extern __shared__ char smem[];
    f16x8* Wlds = (f16x8*)smem;          // [4][24][64] fragments, 96 KB

    const int tid  = threadIdx.x;
    const int lane = tid & 63;
    const int w    = tid >> 6;           // batch n-tile within group
    const int ji   = blockIdx.x & 31;
    const int p    = blockIdx.x >> 5;    // 0..3
    const int gA   = p;
    const int gB   = p + 4;

    {
        const f16x8* src = (const f16x8*)Wp + (size_t)ji * (4*24*64);
        for (int i = tid; i < 4*24*64; i += 256) Wlds[i] = src[i];
    }

    const int uq = (lane >> 4) * 4;      // unit quad within ji's 16 units
    float bias[4][4];
    #pragma unroll
    for (int nt = 0; nt < 4; ++nt)
        #pragma unroll
        for (int r = 0; r < 4; ++r)
            bias[nt][r] = b_ih[nt*512 + ji*16 + uq + r] + b_hh[nt*512 + ji*16 + uq + r];
    __syncthreads();                     // Wlds ready

    const int koff = (lane >> 4) * 8;
    u64* hq = (u64*)hbuf;

    const int batchA = gA*64 + w*16 + (lane & 15);
    const int batchB = gB*64 + w*16 + (lane & 15);
    const float* xrowA = x + (size_t)batchA * TT * DD + koff;
    const float* xrowB = x + (size_t)batchB * TT * DD + koff;
    const int hrowA = (batchA * HH + koff) >> 2;
    const int hrowB = (batchB * HH + koff) >> 2;
    const int hoffA = (batchA * HH + ji*16 + uq) >> 2;
    const int hoffB = (batchB * HH + ji*16 + uq) >> 2;

    float cA[4] = {0.f, 0.f, 0.f, 0.f};
    float cB[4] = {0.f, 0.f, 0.f, 0.f};
    f32x4 accA[4], accB[4];

    // prologue: prime both pipelines with x(0)
    x_tail(0, accA, xrowA, Wlds, bias, lane);
    x_tail(0, accB, xrowB, Wlds, bias, lane);

    for (int s = 0; s < TT; ++s) {
        step_pipe(s, accA, cA, Wlds, hq, hrowA, hoffA, xrowA, bias, lane);
        step_pipe(s, accB, cB, Wlds, hq, hrowB, hoffB, xrowB, bias, lane);
    }

    // ---- classifier head: ji == 0 blocks (p = 0..3) handle groups p, p+4 ----
    if (ji == 0) {
        #pragma unroll 1
        for (int gi = 0; gi < 2; ++gi) {
            const int g = (gi == 0) ? gA : gB;
            const u64* hr = hq + (size_t)(TT & 3) * HQ_SLOT
                          + (((size_t)(g*64 + (tid >> 2)) * HH + (tid & 3)*128) >> 2);
            f16x8 Hh[16];
            for (;;) {
                LDH256_SC1(Hh, hr);
                bool ok = true;
                #pragma unroll
                for (int ks = 0; ks < 16; ++ks) ok = ok && chunk_ok(Hh[ks]);
                if (__all(ok)) break;
                __builtin_amdgcn_s_sleep(2);
            }
            const float* wf = W_fc + (tid & 3)*128;
            float ssum = 0.f;
            #pragma unroll
            for (int c2 = 0; c2 < 16; ++c2)
                #pragma unroll
                for (int e = 0; e < 8; ++e)
                    ssum += (float)Hh[c2][e] * wf[c2*8 + e];
            __syncthreads();             // Wlds (or prior red) no longer needed
            float* red = (float*)smem;   // reuse LDS
            red[(tid >> 2)*4 + (tid & 3)] = ssum;
            __syncthreads();
            if (tid < 64) {
                float v = red[tid*4+0] + red[tid*4+1] + red[tid*4+2] + red[tid*4+3]
                        + b_fc[0];
                out[g*64 + tid] = sigf(v);
            }
            __syncthreads();             // red stable before next group reuses
        }
    }
}

extern "C" void kernel_launch(void* const* d_in, const int* in_sizes, int n_in,
                              void* d_out, int out_size, void* d_ws, size_t ws_size,
                              hipStream_t stream) {
    const float* x    = (const float*)d_in[0];
    const float* W_ih = (const float*)d_in[1];
    const float* W_hh = (const float*)d_in[2];
    const float* b_ih = (const float*)d_in[3];
    const float* b_hh = (const float*)d_in[4];
    const float* W_fc = (const float*)d_in[5];
    const float* b_fc = (const float*)d_in[6];
    float* out = (float*)d_out;

    f16* Wp   = (f16*)d_ws;
    f16* hbuf = (f16*)((char*)d_ws + HBUF_OFF);

    // sentinel-fill h slots (0xFF bytes -> f16 0xFFFF = -NaN everywhere)
    hipMemsetAsync(hbuf, 0xFF, HBUF_BYTES, stream);
    pack_w<<<768, 256, 0, stream>>>(W_ih, W_hh, Wp);

    static bool attr_set = []() {
        hipFuncSetAttribute(reinterpret_cast<const void*>(lstm_fused),
                            hipFuncAttributeMaxDynamicSharedMemorySize, 98304);
        return true;
    }();
    (void)attr_set;

    void* kargs[] = {(void*)&x, (void*)&b_ih, (void*)&b_hh, (void*)&W_fc,
                     (void*)&b_fc, (void*)&Wp, (void*)&hbuf, (void*)&out};
    hipError_t e = hipLaunchCooperativeKernel(
        reinterpret_cast<const void*>(lstm_fused),
        dim3(128), dim3(256), kargs, 98304, stream);
    if (e != hipSuccess) {
        // Fallback: plain launch. 96 KB LDS -> 1 block/CU -> 128 blocks all
        // resident on 256 CUs; persistent-kernel co-residency is structural.
        lstm_fused<<<dim3(128), dim3(256), 98304, stream>>>(
            x, b_ih, b_hh, W_fc, b_fc, Wp, hbuf, out);
    }
}

// Round 15
// 2940.141 us; speedup vs baseline: 1.6870x; 1.6870x over previous
//
#include <hip/hip_runtime.h>

typedef _Float16 f16;
typedef _Float16 f16x8 __attribute__((ext_vector_type(8)));
typedef float f32x4 __attribute__((ext_vector_type(4)));
typedef unsigned int u32;
typedef u32 u32x4 __attribute__((ext_vector_type(4)));
typedef unsigned long long u64;

#define TT 512
#define BB 512
#define DD 256
#define HH 512

// ws layout (bytes)
#define WPACK_BYTES (32*4*24*64*8*2)          // 3,145,728
#define HBUF_OFF    (WPACK_BYTES)
#define HQ_SLOT     (BB*HH/4)                 // u64s per slot = 65536
#define HBUF_BYTES  (4*BB*HH*2)               // 4 rotating slots = 2 MB

__device__ __forceinline__ float sigf(float v) {
    return __frcp_rn(1.0f + __expf(-v));
}
__device__ __forceinline__ float tanh_fast(float v) {
    float e = __expf(2.0f * fminf(v, 15.0f));
    return 1.0f - 2.0f * __frcp_rn(e + 1.0f);
}

// Pre-pack W = [W_ih | W_hh] (f32) into per-block, per-fragment f16 layout:
// Wp[ji][nt][ks][lane][8]  with gate row g = nt*512 + ji*16 + (lane&15),
// k = ks*32 + (lane>>4)*8 + j  (k<256 -> W_ih, else W_hh).
__global__ void pack_w(const float* __restrict__ W_ih,
                       const float* __restrict__ W_hh,
                       f16* __restrict__ Wp) {
    int tid = blockIdx.x * 256 + threadIdx.x;   // 32*4*24*64 = 196608 total
    if (tid >= 32*4*24*64) return;
    int lane = tid & 63;
    int rest = tid >> 6;
    int ks   = rest % 24;
    int t3   = rest / 24;
    int nt   = t3 & 3;
    int ji   = t3 >> 2;
    int g  = nt*512 + ji*16 + (lane & 15);
    int k0 = ks*32 + ((lane >> 4) & 3)*8;
    const float* src = (k0 < 256) ? (W_ih + (size_t)g*DD + k0)
                                  : (W_hh + (size_t)g*HH + (k0 - 256));
    f16x8 v;
    #pragma unroll
    for (int j = 0; j < 8; ++j) v[j] = (f16)src[j];
    *(f16x8*)(Wp + (size_t)tid*8) = v;
}

// 16 x 16B device-scope (sc1) loads at 64B stride, vmcnt(0) fused (no hoist
// gap). Data arrives WITH the freshness markers — single round trip. The
// fused vmcnt(0) also drains last step's clear + x-tail loads: their ack
// latency is absorbed by the h-wait.
#define LDH16_SC1(A, p) asm volatile(                                  \
    "global_load_dwordx4 %0, %16, off sc1\n\t"                         \
    "global_load_dwordx4 %1, %16, off offset:64 sc1\n\t"               \
    "global_load_dwordx4 %2, %16, off offset:128 sc1\n\t"              \
    "global_load_dwordx4 %3, %16, off offset:192 sc1\n\t"              \
    "global_load_dwordx4 %4, %16, off offset:256 sc1\n\t"              \
    "global_load_dwordx4 %5, %16, off offset:320 sc1\n\t"              \
    "global_load_dwordx4 %6, %16, off offset:384 sc1\n\t"              \
    "global_load_dwordx4 %7, %16, off offset:448 sc1\n\t"              \
    "global_load_dwordx4 %8, %16, off offset:512 sc1\n\t"              \
    "global_load_dwordx4 %9, %16, off offset:576 sc1\n\t"              \
    "global_load_dwordx4 %10, %16, off offset:640 sc1\n\t"             \
    "global_load_dwordx4 %11, %16, off offset:704 sc1\n\t"             \
    "global_load_dwordx4 %12, %16, off offset:768 sc1\n\t"             \
    "global_load_dwordx4 %13, %16, off offset:832 sc1\n\t"             \
    "global_load_dwordx4 %14, %16, off offset:896 sc1\n\t"             \
    "global_load_dwordx4 %15, %16, off offset:960 sc1\n\t"             \
    "s_waitcnt vmcnt(0)"                                               \
    : "=&v"((A)[0]), "=&v"((A)[1]), "=&v"((A)[2]), "=&v"((A)[3]),      \
      "=&v"((A)[4]), "=&v"((A)[5]), "=&v"((A)[6]), "=&v"((A)[7]),      \
      "=&v"((A)[8]), "=&v"((A)[9]), "=&v"((A)[10]), "=&v"((A)[11]),    \
      "=&v"((A)[12]), "=&v"((A)[13]), "=&v"((A)[14]), "=&v"((A)[15])   \
    : "v"(p) : "memory")

// 16 x 16B contiguous (256B), sc1, for the classifier head.
#define LDH256_SC1(A, p) asm volatile(                                 \
    "global_load_dwordx4 %0, %16, off sc1\n\t"                         \
    "global_load_dwordx4 %1, %16, off offset:16 sc1\n\t"               \
    "global_load_dwordx4 %2, %16, off offset:32 sc1\n\t"               \
    "global_load_dwordx4 %3, %16, off offset:48 sc1\n\t"               \
    "global_load_dwordx4 %4, %16, off offset:64 sc1\n\t"               \
    "global_load_dwordx4 %5, %16, off offset:80 sc1\n\t"               \
    "global_load_dwordx4 %6, %16, off offset:96 sc1\n\t"               \
    "global_load_dwordx4 %7, %16, off offset:112 sc1\n\t"              \
    "global_load_dwordx4 %8, %16, off offset:128 sc1\n\t"              \
    "global_load_dwordx4 %9, %16, off offset:144 sc1\n\t"              \
    "global_load_dwordx4 %10, %16, off offset:160 sc1\n\t"             \
    "global_load_dwordx4 %11, %16, off offset:176 sc1\n\t"             \
    "global_load_dwordx4 %12, %16, off offset:192 sc1\n\t"             \
    "global_load_dwordx4 %13, %16, off offset:208 sc1\n\t"             \
    "global_load_dwordx4 %14, %16, off offset:224 sc1\n\t"             \
    "global_load_dwordx4 %15, %16, off offset:240 sc1\n\t"             \
    "s_waitcnt vmcnt(0)"                                               \
    : "=&v"((A)[0]), "=&v"((A)[1]), "=&v"((A)[2]), "=&v"((A)[3]),      \
      "=&v"((A)[4]), "=&v"((A)[5]), "=&v"((A)[6]), "=&v"((A)[7]),      \
      "=&v"((A)[8]), "=&v"((A)[9]), "=&v"((A)[10]), "=&v"((A)[11]),    \
      "=&v"((A)[12]), "=&v"((A)[13]), "=&v"((A)[14]), "=&v"((A)[15])   \
    : "v"(p) : "memory")

// Sentinel: f16 0xFFFF (-NaN). h = og*tanh(c) is always finite -> never NaN.
// Each producer lane's 8B quad store is single-instruction atomic, so a chunk
// whose two quad-markers (f16[3], f16[7]) are non-sentinel is complete.
__device__ __forceinline__ bool chunk_ok(const f16x8& c) {
    u32x4 t = __builtin_bit_cast(u32x4, c);
    return ((t.y >> 16) != 0xFFFFu) && ((t.w >> 16) != 0xFFFFu);
}

// Persistent LSTM kernel: 256 blocks x 256 threads. block = (bi = blk&7, ji = blk>>3).
// MFMA roles: A = W (m = 16 gate rows of gate-type nt), B = [x;h] (n = 16 batches).
// R11 sentinel protocol; R15 delta (release de-stall): step order is now
//   poll -> rec MFMA -> cell -> h store -> clear(slot s+3) -> x tail
// with NO pre-store vmcnt(0). The clear & h-store hit different slots (no
// ordering needed); the clear's only requirement — complete before my own
// h(s+3) store two steps later — is enforced for free by the fused vmcnt(0)
// inside the NEXT step's poll. The h store reaches L3 ~0.3-0.8us earlier.
__launch_bounds__(256, 1)
__global__ void lstm_fused(const float* __restrict__ x,
                           const float* __restrict__ b_ih,
                           const float* __restrict__ b_hh,
                           const float* __restrict__ W_fc,
                           const float* __restrict__ b_fc,
                           const f16* __restrict__ Wp,
                           f16* __restrict__ hbuf,
                           float* __restrict__ out) {
    extern __shared__ char smem[];
    f16x8* Wlds = (f16x8*)smem;          // [4][24][64] fragments, 96 KB

    const int tid  = threadIdx.x;
    const int lane = tid & 63;
    const int w    = tid >> 6;           // batch n-tile within group
    const int bi   = blockIdx.x & 7;
    const int ji   = blockIdx.x >> 3;

    {
        const f16x8* src = (const f16x8*)Wp + (size_t)ji * (4*24*64);
        for (int i = tid; i < 4*24*64; i += 256) Wlds[i] = src[i];
    }

    const int uq = (lane >> 4) * 4;      // unit quad within ji's 16 units
    float bias[4][4];
    #pragma unroll
    for (int nt = 0; nt < 4; ++nt)
        #pragma unroll
        for (int r = 0; r < 4; ++r)
            bias[nt][r] = b_ih[nt*512 + ji*16 + uq + r] + b_hh[nt*512 + ji*16 + uq + r];
    __syncthreads();                     // Wlds ready

    const int batch  = bi*64 + w*16 + (lane & 15);
    const int koff   = (lane >> 4) * 8;
    const float* xrow = x + (size_t)batch * TT * DD + koff;
    u64* hq = (u64*)hbuf;
    const int hrow_q = (batch * HH + koff) >> 2;                // consumer u64 idx
    const int hoff_q = (batch * HH + ji*16 + uq) >> 2;          // producer u64 idx

    float c[4] = {0.f, 0.f, 0.f, 0.f};
    f32x4 acc[4];

    // ---- prologue: acc = bias + x(0) * W_ih ----
    {
        float4 xa[8], xb[8];
        #pragma unroll
        for (int ks = 0; ks < 8; ++ks) {
            xa[ks] = *(const float4*)(xrow + ks*32);
            xb[ks] = *(const float4*)(xrow + ks*32 + 4);
        }
        #pragma unroll
        for (int nt = 0; nt < 4; ++nt)
            acc[nt] = (f32x4){bias[nt][0], bias[nt][1], bias[nt][2], bias[nt][3]};
        #pragma unroll
        for (int ks = 0; ks < 8; ++ks) {
            f16x8 a;
            a[0]=(f16)xa[ks].x; a[1]=(f16)xa[ks].y; a[2]=(f16)xa[ks].z; a[3]=(f16)xa[ks].w;
            a[4]=(f16)xb[ks].x; a[5]=(f16)xb[ks].y; a[6]=(f16)xb[ks].z; a[7]=(f16)xb[ks].w;
            #pragma unroll
            for (int nt = 0; nt < 4; ++nt)
                acc[nt] = __builtin_amdgcn_mfma_f32_16x16x32_f16(
                    Wlds[(nt*24 + ks)*64 + lane], a, acc[nt], 0, 0, 0);
        }
    }

    for (int s = 0; s < TT; ++s) {
        // ---- 1. recurrent part: single-RTT sentinel poll-with-data + MFMA ----
        if (s > 0) {
            const u64* hb = hq + (size_t)(s & 3) * HQ_SLOT + hrow_q;
            f16x8 Ah[16];
            for (;;) {
                LDH16_SC1(Ah, hb);
                bool ok = true;
                #pragma unroll
                for (int ks = 0; ks < 16; ++ks) ok = ok && chunk_ok(Ah[ks]);
                if (__all(ok)) break;
                __builtin_amdgcn_s_sleep(2);
            }
            #pragma unroll
            for (int ks = 0; ks < 16; ++ks)
                #pragma unroll
                for (int nt = 0; nt < 4; ++nt)
                    acc[nt] = __builtin_amdgcn_mfma_f32_16x16x32_f16(
                        Wlds[(nt*24 + ks + 8)*64 + lane], Ah[ks], acc[nt], 0, 0, 0);
        }

        // ---- 2. cell: lane = (batch, units uq..uq+3) for all 4 gates ----
        union { u64 q; f16 h4[4]; } H;
        #pragma unroll
        for (int r = 0; r < 4; ++r) {
            float ig = sigf(acc[0][r]);
            float fg = sigf(acc[1][r]);
            float gg = tanh_fast(acc[2][r]);
            float og = sigf(acc[3][r]);
            c[r] = fg * c[r] + ig * gg;
            H.h4[r] = (f16)(og * tanh_fast(c[r]));
        }

        // ---- 3. release FIRST: h store with nothing in front of it ----
        __hip_atomic_store(hq + (size_t)((s + 1) & 3) * HQ_SLOT + hoff_q, H.q,
                           __ATOMIC_RELAXED, __HIP_MEMORY_SCOPE_AGENT);

        // ---- 4. clear own region of slot (s+3)%4 for h(s+3), AFTER the
        //         store (different slot, no ordering needed). Safe: this
        //         step's full verification proved the community finished
        //         reading h(s-1) (the data being cleared); completion is
        //         enforced by the next poll's fused vmcnt(0), two steps
        //         before the region is rewritten. ----
        if (s + 3 <= TT)
            __hip_atomic_store(hq + (size_t)((s + 3) & 3) * HQ_SLOT + hoff_q,
                               0xFFFFFFFFFFFFFFFFull, __ATOMIC_RELAXED,
                               __HIP_MEMORY_SCOPE_AGENT);

        // ---- 5. tail (off peer-critical path): x(s+1) tight burst + MFMA ----
        if (s + 1 < TT) {
            const float* xs = xrow + (size_t)(s + 1) * DD;
            float4 na[8], nb[8];
            #pragma unroll
            for (int ks = 0; ks < 8; ++ks) {
                na[ks] = *(const float4*)(xs + ks*32);
                nb[ks] = *(const float4*)(xs + ks*32 + 4);
            }
            #pragma unroll
            for (int nt = 0; nt < 4; ++nt)
                acc[nt] = (f32x4){bias[nt][0], bias[nt][1], bias[nt][2], bias[nt][3]};
            #pragma unroll
            for (int ks = 0; ks < 8; ++ks) {
                f16x8 a;
                a[0]=(f16)na[ks].x; a[1]=(f16)na[ks].y; a[2]=(f16)na[ks].z; a[3]=(f16)na[ks].w;
                a[4]=(f16)nb[ks].x; a[5]=(f16)nb[ks].y; a[6]=(f16)nb[ks].z; a[7]=(f16)nb[ks].w;
                #pragma unroll
                for (int nt = 0; nt < 4; ++nt)
                    acc[nt] = __builtin_amdgcn_mfma_f32_16x16x32_f16(
                        Wlds[(nt*24 + ks)*64 + lane], a, acc[nt], 0, 0, 0);
            }
        }
    }

    // ---- classifier head: blocks with ji == 0, one per batch group ----
    if (ji == 0) {
        const u64* hr = hq + (size_t)(TT & 3) * HQ_SLOT
                      + (((size_t)(bi*64 + (tid >> 2)) * HH + (tid & 3)*128) >> 2);
        f16x8 Hh[16];
        for (;;) {
            LDH256_SC1(Hh, hr);
            bool ok = true;
            #pragma unroll
            for (int ks = 0; ks < 16; ++ks) ok = ok && chunk_ok(Hh[ks]);
            if (__all(ok)) break;
            __builtin_amdgcn_s_sleep(2);
        }
        const float* wf = W_fc + (tid & 3)*128;
        float ssum = 0.f;
        #pragma unroll
        for (int c2 = 0; c2 < 16; ++c2)
            #pragma unroll
            for (int e = 0; e < 8; ++e)
                ssum += (float)Hh[c2][e] * wf[c2*8 + e];
        __syncthreads();                 // all waves done with Wlds
        float* red = (float*)smem;       // reuse LDS
        red[(tid >> 2)*4 + (tid & 3)] = ssum;
        __syncthreads();
        if (tid < 64) {
            float v = red[tid*4+0] + red[tid*4+1] + red[tid*4+2] + red[tid*4+3] + b_fc[0];
            out[bi*64 + tid] = sigf(v);
        }
    }
}

extern "C" void kernel_launch(void* const* d_in, const int* in_sizes, int n_in,
                              void* d_out, int out_size, void* d_ws, size_t ws_size,
                              hipStream_t stream) {
    const float* x    = (const float*)d_in[0];
    const float* W_ih = (const float*)d_in[1];
    const float* W_hh = (const float*)d_in[2];
    const float* b_ih = (const float*)d_in[3];
    const float* b_hh = (const float*)d_in[4];
    const float* W_fc = (const float*)d_in[5];
    const float* b_fc = (const float*)d_in[6];
    float* out = (float*)d_out;

    f16* Wp   = (f16*)d_ws;
    f16* hbuf = (f16*)((char*)d_ws + HBUF_OFF);

    // sentinel-fill h slots (0xFF bytes -> f16 0xFFFF = -NaN everywhere)
    hipMemsetAsync(hbuf, 0xFF, HBUF_BYTES, stream);
    pack_w<<<768, 256, 0, stream>>>(W_ih, W_hh, Wp);

    static bool attr_set = []() {
        hipFuncSetAttribute(reinterpret_cast<const void*>(lstm_fused),
                            hipFuncAttributeMaxDynamicSharedMemorySize, 98304);
        return true;
    }();
    (void)attr_set;

    void* kargs[] = {(void*)&x, (void*)&b_ih, (void*)&b_hh, (void*)&W_fc,
                     (void*)&b_fc, (void*)&Wp, (void*)&hbuf, (void*)&out};
    hipError_t e = hipLaunchCooperativeKernel(
        reinterpret_cast<const void*>(lstm_fused),
        dim3(256), dim3(256), kargs, 98304, stream);
    if (e != hipSuccess) {
        // Fallback: plain launch. Same semantics here: 96 KB LDS ->
        // 1 block/CU -> all 256 blocks resident.
        lstm_fused<<<dim3(256), dim3(256), 98304, stream>>>(
            x, b_ih, b_hh, W_fc, b_fc, Wp, hbuf, out);
    }
}

// Round 16
// 2611.288 us; speedup vs baseline: 1.8995x; 1.1259x over previous
//
#include <hip/hip_runtime.h>

typedef _Float16 f16;
typedef _Float16 f16x8 __attribute__((ext_vector_type(8)));
typedef float f32x4 __attribute__((ext_vector_type(4)));
typedef unsigned int u32;
typedef u32 u32x4 __attribute__((ext_vector_type(4)));
typedef unsigned long long u64;

#define TT 512
#define BB 512
#define DD 256
#define HH 512

// ws layout (bytes)
#define WPACK_BYTES (32*4*24*64*8*2)          // 3,145,728
#define HBUF_OFF    (WPACK_BYTES)
#define HQ_SLOT     (BB*HH/4)                 // u64s per slot = 65536
#define HBUF_BYTES  (4*BB*HH*2)               // 4 rotating slots = 2 MB

__device__ __forceinline__ float sigf(float v) {
    return __frcp_rn(1.0f + __expf(-v));
}
__device__ __forceinline__ float tanh_fast(float v) {
    float e = __expf(2.0f * fminf(v, 15.0f));
    return 1.0f - 2.0f * __frcp_rn(e + 1.0f);
}

// Pre-pack W = [W_ih | W_hh] (f32) into per-block, per-fragment f16 layout:
// Wp[ji][nt][ks][lane][8]  with gate row g = nt*512 + ji*16 + (lane&15),
// k = ks*32 + (lane>>4)*8 + j  (k<256 -> W_ih, else W_hh).
__global__ void pack_w(const float* __restrict__ W_ih,
                       const float* __restrict__ W_hh,
                       f16* __restrict__ Wp) {
    int tid = blockIdx.x * 256 + threadIdx.x;   // 32*4*24*64 = 196608 total
    if (tid >= 32*4*24*64) return;
    int lane = tid & 63;
    int rest = tid >> 6;
    int ks   = rest % 24;
    int t3   = rest / 24;
    int nt   = t3 & 3;
    int ji   = t3 >> 2;
    int g  = nt*512 + ji*16 + (lane & 15);
    int k0 = ks*32 + ((lane >> 4) & 3)*8;
    const float* src = (k0 < 256) ? (W_ih + (size_t)g*DD + k0)
                                  : (W_hh + (size_t)g*HH + (k0 - 256));
    f16x8 v;
    #pragma unroll
    for (int j = 0; j < 8; ++j) v[j] = (f16)src[j];
    *(f16x8*)(Wp + (size_t)tid*8) = v;
}

// 16 x 16B device-scope (sc1) loads at 64B stride, vmcnt(0) fused (no hoist
// gap). Data arrives WITH the freshness markers — single round trip.
#define LDH16_SC1(A, p) asm volatile(                                  \
    "global_load_dwordx4 %0, %16, off sc1\n\t"                         \
    "global_load_dwordx4 %1, %16, off offset:64 sc1\n\t"               \
    "global_load_dwordx4 %2, %16, off offset:128 sc1\n\t"              \
    "global_load_dwordx4 %3, %16, off offset:192 sc1\n\t"              \
    "global_load_dwordx4 %4, %16, off offset:256 sc1\n\t"              \
    "global_load_dwordx4 %5, %16, off offset:320 sc1\n\t"              \
    "global_load_dwordx4 %6, %16, off offset:384 sc1\n\t"              \
    "global_load_dwordx4 %7, %16, off offset:448 sc1\n\t"              \
    "global_load_dwordx4 %8, %16, off offset:512 sc1\n\t"              \
    "global_load_dwordx4 %9, %16, off offset:576 sc1\n\t"              \
    "global_load_dwordx4 %10, %16, off offset:640 sc1\n\t"             \
    "global_load_dwordx4 %11, %16, off offset:704 sc1\n\t"             \
    "global_load_dwordx4 %12, %16, off offset:768 sc1\n\t"             \
    "global_load_dwordx4 %13, %16, off offset:832 sc1\n\t"             \
    "global_load_dwordx4 %14, %16, off offset:896 sc1\n\t"             \
    "global_load_dwordx4 %15, %16, off offset:960 sc1\n\t"             \
    "s_waitcnt vmcnt(0)"                                               \
    : "=&v"((A)[0]), "=&v"((A)[1]), "=&v"((A)[2]), "=&v"((A)[3]),      \
      "=&v"((A)[4]), "=&v"((A)[5]), "=&v"((A)[6]), "=&v"((A)[7]),      \
      "=&v"((A)[8]), "=&v"((A)[9]), "=&v"((A)[10]), "=&v"((A)[11]),    \
      "=&v"((A)[12]), "=&v"((A)[13]), "=&v"((A)[14]), "=&v"((A)[15])   \
    : "v"(p) : "memory")

// 16 x 16B contiguous (256B), sc1, for the classifier head.
#define LDH256_SC1(A, p) asm volatile(                                 \
    "global_load_dwordx4 %0, %16, off sc1\n\t"                         \
    "global_load_dwordx4 %1, %16, off offset:16 sc1\n\t"               \
    "global_load_dwordx4 %2, %16, off offset:32 sc1\n\t"               \
    "global_load_dwordx4 %3, %16, off offset:48 sc1\n\t"               \
    "global_load_dwordx4 %4, %16, off offset:64 sc1\n\t"               \
    "global_load_dwordx4 %5, %16, off offset:80 sc1\n\t"               \
    "global_load_dwordx4 %6, %16, off offset:96 sc1\n\t"               \
    "global_load_dwordx4 %7, %16, off offset:112 sc1\n\t"              \
    "global_load_dwordx4 %8, %16, off offset:128 sc1\n\t"              \
    "global_load_dwordx4 %9, %16, off offset:144 sc1\n\t"              \
    "global_load_dwordx4 %10, %16, off offset:160 sc1\n\t"             \
    "global_load_dwordx4 %11, %16, off offset:176 sc1\n\t"             \
    "global_load_dwordx4 %12, %16, off offset:192 sc1\n\t"             \
    "global_load_dwordx4 %13, %16, off offset:208 sc1\n\t"             \
    "global_load_dwordx4 %14, %16, off offset:224 sc1\n\t"             \
    "global_load_dwordx4 %15, %16, off offset:240 sc1\n\t"             \
    "s_waitcnt vmcnt(0)"                                               \
    : "=&v"((A)[0]), "=&v"((A)[1]), "=&v"((A)[2]), "=&v"((A)[3]),      \
      "=&v"((A)[4]), "=&v"((A)[5]), "=&v"((A)[6]), "=&v"((A)[7]),      \
      "=&v"((A)[8]), "=&v"((A)[9]), "=&v"((A)[10]), "=&v"((A)[11]),    \
      "=&v"((A)[12]), "=&v"((A)[13]), "=&v"((A)[14]), "=&v"((A)[15])   \
    : "v"(p) : "memory")

// Sentinel: f16 0xFFFF (-NaN). h = og*tanh(c) is always finite -> never NaN.
// Each producer lane's 8B quad store is single-instruction atomic, so a chunk
// whose two quad-markers (f16[3], f16[7]) are non-sentinel is complete.
__device__ __forceinline__ bool chunk_ok(const f16x8& c) {
    u32x4 t = __builtin_bit_cast(u32x4, c);
    return ((t.y >> 16) != 0xFFFFu) && ((t.w >> 16) != 0xFFFFu);
}

// Persistent LSTM kernel: 256 blocks x 256 threads. block = (bi = blk&7, ji = blk>>3).
// MFMA roles: A = W (m = 16 gate rows of gate-type nt), B = [x;h] (n = 16 batches).
// R11 (empirical optimum, 2629 us): in-band freshness. h buffer = 4 rotating
// slots, memset to sentinel per launch. Consumer polls its h chunks directly
// (data + validity in ONE sc1 load round trip). Producer: clear own region of
// slot (s+3)%4 after poll (safe: poll h(s) success => community (bi,*,w)
// finished reading h(s-1), the data being cleared), vmcnt(0) (drains the
// overlapped clear so the h store enters an empty queue), 8B h store, DONE —
// no ack wait, no flags. NOTE (R15 lesson): the pre-store vmcnt(0) and the
// clear-before-MFMA placement are PERF-CRITICAL — reordering costs ~12%.
__launch_bounds__(256, 1)
__global__ void lstm_fused(const float* __restrict__ x,
                           const float* __restrict__ b_ih,
                           const float* __restrict__ b_hh,
                           const float* __restrict__ W_fc,
                           const float* __restrict__ b_fc,
                           const f16* __restrict__ Wp,
                           f16* __restrict__ hbuf,
                           float* __restrict__ out) {
    extern __shared__ char smem[];
    f16x8* Wlds = (f16x8*)smem;          // [4][24][64] fragments, 96 KB

    const int tid  = threadIdx.x;
    const int lane = tid & 63;
    const int w    = tid >> 6;           // batch n-tile within group
    const int bi   = blockIdx.x & 7;
    const int ji   = blockIdx.x >> 3;

    {
        const f16x8* src = (const f16x8*)Wp + (size_t)ji * (4*24*64);
        for (int i = tid; i < 4*24*64; i += 256) Wlds[i] = src[i];
    }

    const int uq = (lane >> 4) * 4;      // unit quad within ji's 16 units
    float bias[4][4];
    #pragma unroll
    for (int nt = 0; nt < 4; ++nt)
        #pragma unroll
        for (int r = 0; r < 4; ++r)
            bias[nt][r] = b_ih[nt*512 + ji*16 + uq + r] + b_hh[nt*512 + ji*16 + uq + r];
    __syncthreads();                     // Wlds ready

    const int batch  = bi*64 + w*16 + (lane & 15);
    const int koff   = (lane >> 4) * 8;
    const float* xrow = x + (size_t)batch * TT * DD + koff;
    u64* hq = (u64*)hbuf;
    const int hrow_q = (batch * HH + koff) >> 2;                // consumer u64 idx
    const int hoff_q = (batch * HH + ji*16 + uq) >> 2;          // producer u64 idx

    float c[4] = {0.f, 0.f, 0.f, 0.f};
    f32x4 acc[4];

    // ---- prologue: acc = bias + x(0) * W_ih ----
    {
        float4 xa[8], xb[8];
        #pragma unroll
        for (int ks = 0; ks < 8; ++ks) {
            xa[ks] = *(const float4*)(xrow + ks*32);
            xb[ks] = *(const float4*)(xrow + ks*32 + 4);
        }
        #pragma unroll
        for (int nt = 0; nt < 4; ++nt)
            acc[nt] = (f32x4){bias[nt][0], bias[nt][1], bias[nt][2], bias[nt][3]};
        #pragma unroll
        for (int ks = 0; ks < 8; ++ks) {
            f16x8 a;
            a[0]=(f16)xa[ks].x; a[1]=(f16)xa[ks].y; a[2]=(f16)xa[ks].z; a[3]=(f16)xa[ks].w;
            a[4]=(f16)xb[ks].x; a[5]=(f16)xb[ks].y; a[6]=(f16)xb[ks].z; a[7]=(f16)xb[ks].w;
            #pragma unroll
            for (int nt = 0; nt < 4; ++nt)
                acc[nt] = __builtin_amdgcn_mfma_f32_16x16x32_f16(
                    Wlds[(nt*24 + ks)*64 + lane], a, acc[nt], 0, 0, 0);
        }
    }

    for (int s = 0; s < TT; ++s) {
        // ---- 1. recurrent part: single-RTT sentinel poll-with-data + MFMA ----
        if (s > 0) {
            const u64* hb = hq + (size_t)(s & 3) * HQ_SLOT + hrow_q;
            f16x8 Ah[16];
            for (;;) {
                LDH16_SC1(Ah, hb);
                bool ok = true;
                #pragma unroll
                for (int ks = 0; ks < 16; ++ks) ok = ok && chunk_ok(Ah[ks]);
                if (__all(ok)) break;
                __builtin_amdgcn_s_sleep(2);
            }
            // clear own region of slot (s+3)%4 for h(s+3): poll success proves
            // community (bi,*,w) finished reading h(s-1) (same slot).
            if (s + 3 <= TT)
                __hip_atomic_store(hq + (size_t)((s + 3) & 3) * HQ_SLOT + hoff_q,
                                   0xFFFFFFFFFFFFFFFFull, __ATOMIC_RELAXED,
                                   __HIP_MEMORY_SCOPE_AGENT);
            #pragma unroll
            for (int ks = 0; ks < 16; ++ks)
                #pragma unroll
                for (int nt = 0; nt < 4; ++nt)
                    acc[nt] = __builtin_amdgcn_mfma_f32_16x16x32_f16(
                        Wlds[(nt*24 + ks + 8)*64 + lane], Ah[ks], acc[nt], 0, 0, 0);
        } else {
            // s == 0: slot 3 untouched (sentinel from memset); issue its clear
            // anyway for uniformity — harmless, nothing has read it.
            __hip_atomic_store(hq + (size_t)3 * HQ_SLOT + hoff_q,
                               0xFFFFFFFFFFFFFFFFull, __ATOMIC_RELAXED,
                               __HIP_MEMORY_SCOPE_AGENT);
        }

        // ---- 2. cell: lane = (batch, units uq..uq+3) for all 4 gates ----
        union { u64 q; f16 h4[4]; } H;
        #pragma unroll
        for (int r = 0; r < 4; ++r) {
            float ig = sigf(acc[0][r]);
            float fg = sigf(acc[1][r]);
            float gg = tanh_fast(acc[2][r]);
            float og = sigf(acc[3][r]);
            c[r] = fg * c[r] + ig * gg;
            H.h4[r] = (f16)(og * tanh_fast(c[r]));
        }

        // ---- 3. release: drain the (old, overlapped) clear, store h, done ----
        asm volatile("s_waitcnt vmcnt(0)" ::: "memory");
        __hip_atomic_store(hq + (size_t)((s + 1) & 3) * HQ_SLOT + hoff_q, H.q,
                           __ATOMIC_RELAXED, __HIP_MEMORY_SCOPE_AGENT);

        // ---- 4. tail (off critical path): x(s+1) load + x-MFMA ----
        if (s + 1 < TT) {
            const float* xs = xrow + (size_t)(s + 1) * DD;
            float4 na[8], nb[8];
            #pragma unroll
            for (int ks = 0; ks < 8; ++ks) {
                na[ks] = *(const float4*)(xs + ks*32);
                nb[ks] = *(const float4*)(xs + ks*32 + 4);
            }
            #pragma unroll
            for (int nt = 0; nt < 4; ++nt)
                acc[nt] = (f32x4){bias[nt][0], bias[nt][1], bias[nt][2], bias[nt][3]};
            #pragma unroll
            for (int ks = 0; ks < 8; ++ks) {
                f16x8 a;
                a[0]=(f16)na[ks].x; a[1]=(f16)na[ks].y; a[2]=(f16)na[ks].z; a[3]=(f16)na[ks].w;
                a[4]=(f16)nb[ks].x; a[5]=(f16)nb[ks].y; a[6]=(f16)nb[ks].z; a[7]=(f16)nb[ks].w;
                #pragma unroll
                for (int nt = 0; nt < 4; ++nt)
                    acc[nt] = __builtin_amdgcn_mfma_f32_16x16x32_f16(
                        Wlds[(nt*24 + ks)*64 + lane], a, acc[nt], 0, 0, 0);
            }
        }
    }

    // ---- classifier head: blocks with ji == 0, one per batch group ----
    if (ji == 0) {
        const u64* hr = hq + (size_t)(TT & 3) * HQ_SLOT
                      + (((size_t)(bi*64 + (tid >> 2)) * HH + (tid & 3)*128) >> 2);
        f16x8 Hh[16];
        for (;;) {
            LDH256_SC1(Hh, hr);
            bool ok = true;
            #pragma unroll
            for (int ks = 0; ks < 16; ++ks) ok = ok && chunk_ok(Hh[ks]);
            if (__all(ok)) break;
            __builtin_amdgcn_s_sleep(2);
        }
        const float* wf = W_fc + (tid & 3)*128;
        float ssum = 0.f;
        #pragma unroll
        for (int c2 = 0; c2 < 16; ++c2)
            #pragma unroll
            for (int e = 0; e < 8; ++e)
                ssum += (float)Hh[c2][e] * wf[c2*8 + e];
        __syncthreads();                 // all waves done with Wlds
        float* red = (float*)smem;       // reuse LDS
        red[(tid >> 2)*4 + (tid & 3)] = ssum;
        __syncthreads();
        if (tid < 64) {
            float v = red[tid*4+0] + red[tid*4+1] + red[tid*4+2] + red[tid*4+3] + b_fc[0];
            out[bi*64 + tid] = sigf(v);
        }
    }
}

extern "C" void kernel_launch(void* const* d_in, const int* in_sizes, int n_in,
                              void* d_out, int out_size, void* d_ws, size_t ws_size,
                              hipStream_t stream) {
    const float* x    = (const float*)d_in[0];
    const float* W_ih = (const float*)d_in[1];
    const float* W_hh = (const float*)d_in[2];
    const float* b_ih = (const float*)d_in[3];
    const float* b_hh = (const float*)d_in[4];
    const float* W_fc = (const float*)d_in[5];
    const float* b_fc = (const float*)d_in[6];
    float* out = (float*)d_out;

    f16* Wp   = (f16*)d_ws;
    f16* hbuf = (f16*)((char*)d_ws + HBUF_OFF);

    // sentinel-fill h slots (0xFF bytes -> f16 0xFFFF = -NaN everywhere)
    hipMemsetAsync(hbuf, 0xFF, HBUF_BYTES, stream);
    pack_w<<<768, 256, 0, stream>>>(W_ih, W_hh, Wp);

    static bool attr_set = []() {
        hipFuncSetAttribute(reinterpret_cast<const void*>(lstm_fused),
                            hipFuncAttributeMaxDynamicSharedMemorySize, 98304);
        return true;
    }();
    (void)attr_set;

    void* kargs[] = {(void*)&x, (void*)&b_ih, (void*)&b_hh, (void*)&W_fc,
                     (void*)&b_fc, (void*)&Wp, (void*)&hbuf, (void*)&out};
    hipError_t e = hipLaunchCooperativeKernel(
        reinterpret_cast<const void*>(lstm_fused),
        dim3(256), dim3(256), kargs, 98304, stream);
    if (e != hipSuccess) {
        // Fallback: plain launch. Same semantics here: 96 KB LDS ->
        // 1 block/CU -> all 256 blocks resident.
        lstm_fused<<<dim3(256), dim3(256), 98304, stream>>>(
            x, b_ih, b_hh, W_fc, b_fc, Wp, hbuf, out);
    }
}